// Round 17
// baseline (50799.655 us; speedup 1.0000x reference)
//
#include <hip/hip_runtime.h>

#define D 64
// XCD-private dim-sliced SpMM: D=64 split into 8 slices of 8 floats. One slice
// = N*32B = 2.88 MB < 4 MB L2, so a slice is FULLY L2-resident (no tiles, no
// phasing). Each block discovers its physical XCD via s_getreg(HW_REG_XCC_ID)
// and pops node-chunks from that XCD's atomic queue -> slice s is read and
// written ONLY by XCD s, regardless of how blocks are dispatched. Gathers are
// float4/lane (2 lanes per 32B row; one dwordx4 instr moves 32 rows/wave).
// Round-12/13 lessons: no nontemporal anywhere; per-edge instruction count is
// as important as L2-miss bytes.

__global__ void degree_kernel(const int* __restrict__ col, int* __restrict__ deg, int E) {
    int e = blockIdx.x * blockDim.x + threadIdx.x;
    if (e < E) atomicAdd(&deg[col[e]], 1);
}

__global__ void dinv_kernel(const int* __restrict__ deg, float* __restrict__ dinv, int n) {
    int i = blockIdx.x * blockDim.x + threadIdx.x;
    if (i < n) {
        int d = deg[i];
        dinv[i] = (d > 0) ? rsqrtf((float)d) : 0.0f;
    }
}

// Single-workgroup exclusive scan over N elements (runs once per call).
__global__ __launch_bounds__(1024) void scan_kernel(const int* __restrict__ deg,
                                                    int* __restrict__ row_ptr, int n) {
    __shared__ int wsum[16];
    const int tid = threadIdx.x;
    const int lane = tid & 63;
    const int w = tid >> 6;
    int carry = 0;
    for (int base = 0; base < n; base += 1024) {
        int i = base + tid;
        int v = (i < n) ? deg[i] : 0;
        int x = v;
#pragma unroll
        for (int off = 1; off < 64; off <<= 1) {
            int y = __shfl_up(x, off);
            if (lane >= off) x += y;
        }
        if (lane == 63) wsum[w] = x;
        __syncthreads();
        if (w == 0 && lane < 16) {
            int s = wsum[lane];
#pragma unroll
            for (int off = 1; off < 16; off <<= 1) {
                int y = __shfl_up(s, off);
                if (lane >= off) s += y;
            }
            wsum[lane] = s;
        }
        __syncthreads();
        int pref = (w > 0) ? wsum[w - 1] : 0;
        if (i < n) row_ptr[i] = carry + pref + (x - v);
        carry += wsum[15];
        __syncthreads();
    }
    if (tid == 0) row_ptr[n] = carry;
}

// simple CSR build: only src ids (y-transform removed per-edge weights)
__global__ void scatter_kernel(const int* __restrict__ row, const int* __restrict__ col,
                               const int* __restrict__ row_ptr, int* __restrict__ cursor,
                               int* __restrict__ csr_src, int E) {
    int e = blockIdx.x * blockDim.x + threadIdx.x;
    if (e < E) {
        int s = row[e];
        int d = col[e];
        int pos = row_ptr[d] + atomicAdd(&cursor[d], 1);
        csr_src[pos] = s;
    }
}

// y0 = dinv ⊙ emb, acc0 = emb, both in sliced layout:
// float4 index = (s*n + node)*2 + h,  s=0..7 (slice), h=0..1 (float4 in 32B row)
__global__ void init_kernel(const float4* __restrict__ emb, const float* __restrict__ dinv,
                            float4* __restrict__ y, float4* __restrict__ accS, int n) {
    int i = blockIdx.x * blockDim.x + threadIdx.x;   // over n*16 float4s
    if (i < n * 16) {
        int node = i >> 4;
        int rr = i & 15;
        int s = rr >> 1;
        int h = rr & 1;
        float dv = dinv[node];
        float4 v = emb[i];
        size_t idx = ((size_t)s * n + node) * 2 + h;
        accS[idx] = v;
        float4 yv;
        yv.x = v.x * dv; yv.y = v.y * dv; yv.z = v.z * dv; yv.w = v.w * dv;
        y[idx] = yv;
    }
}

// Wave layout: 32 node-slots x 2 lanes. Slot p (lanes 2p,2p+1) walks node v's
// whole edge list serially; lane r holds float4 r of the node's 32B slice row.
// One gather instruction = 32 rows. Indices are software-pipelined 1 ahead.
// Blocks pop 128-node chunks from their own XCD's queue until empty.
__global__ __launch_bounds__(256) void spmm8_kernel(
    const float* __restrict__ y_in, float* __restrict__ y_out,
    float* __restrict__ accS, const int* __restrict__ row_ptr,
    const int* __restrict__ csr_src, const float* __restrict__ dinv,
    int* __restrict__ queue, int n, int nchunks, int E) {
    int xcd;
    asm volatile("s_getreg_b32 %0, hwreg(HW_REG_XCC_ID)" : "=s"(xcd));
    xcd &= 7;
    const int wv = threadIdx.x >> 6;
    const int lane = threadIdx.x & 63;
    const int slot = lane >> 1;          // node slot 0..31
    const int r = lane & 1;              // float4 within 32B row
    const int Em1 = E - 1;
    const float* __restrict__ yb = y_in + (size_t)xcd * n * 8;
    float* __restrict__ yo = y_out + (size_t)xcd * n * 8;
    float* __restrict__ ao = accS + (size_t)xcd * n * 8;

    __shared__ int chunk_sh;
    for (;;) {
        if (threadIdx.x == 0) chunk_sh = atomicAdd(&queue[xcd], 1);
        __syncthreads();
        const int chunk = chunk_sh;
        if (chunk >= nchunks) break;

        const int v = chunk * 128 + wv * 32 + slot;
        int beg = 0, len = 0;
        if (v < n) {
            beg = row_ptr[v];
            len = row_ptr[v + 1] - beg;
        }
        float4 acc; acc.x = acc.y = acc.z = acc.w = 0.f;

        // software pipeline: index for step k loaded at step k-1
        int e0 = (beg < Em1) ? beg : Em1;
        int idx0 = csr_src[e0];
        for (int k = 0; k < len; ++k) {
            const int kn = k + 1;
            int en = beg + ((kn < len) ? kn : 0);
            en = (en < Em1) ? en : Em1;
            const int idxn = csr_src[en];
            const float4 g = *(const float4*)(yb + (size_t)idx0 * 8 + r * 4);
            acc.x += g.x; acc.y += g.y; acc.z += g.z; acc.w += g.w;
            idx0 = idxn;
        }

        if (v < n) {
            const float dv = dinv[v];
            float4 xn;
            xn.x = dv * acc.x; xn.y = dv * acc.y; xn.z = dv * acc.z; xn.w = dv * acc.w;
            float* ap = ao + (size_t)v * 8 + r * 4;
            float4 a = *(const float4*)ap;
            a.x += xn.x; a.y += xn.y; a.z += xn.z; a.w += xn.w;
            *(float4*)ap = a;
            float4 yn;
            yn.x = dv * xn.x; yn.y = dv * xn.y; yn.z = dv * xn.z; yn.w = dv * xn.w;
            *(float4*)(yo + (size_t)v * 8 + r * 4) = yn;
        }
        __syncthreads();   // all lanes done with chunk_sh before next pop
    }
}

// Un-transpose the sliced accumulator into d_out and apply the 1/(L+1) scale.
__global__ void finalize_kernel(const float4* __restrict__ accS, float4* __restrict__ out,
                                float f, int n) {
    int i = blockIdx.x * blockDim.x + threadIdx.x;   // over n*16 float4s
    if (i < n * 16) {
        int node = i >> 4;
        int rr = i & 15;
        int s = rr >> 1;
        int h = rr & 1;
        float4 a = accS[((size_t)s * n + node) * 2 + h];
        a.x *= f; a.y *= f; a.z *= f; a.w *= f;
        out[i] = a;
    }
}

extern "C" void kernel_launch(void* const* d_in, const int* in_sizes, int n_in,
                              void* d_out, int out_size, void* d_ws, size_t ws_size,
                              hipStream_t stream) {
    const float* emb = (const float*)d_in[0];
    const int* eidx = (const int*)d_in[1];
    const int N = in_sizes[0] / D;   // 90000
    const int E = in_sizes[1] / 2;   // 3000000
    const int L = 100;
    const int* row = eidx;       // edge_index[0]
    const int* col = eidx + E;   // edge_index[1]

    size_t off = 0;
    auto alloc = [&](size_t bytes) -> void* {
        void* p = (char*)d_ws + off;
        off += (bytes + 255) & ~(size_t)255;
        return p;
    };
    int*   deg     = (int*)alloc((size_t)N * 4);
    float* dinv    = (float*)alloc((size_t)N * 4);
    int*   row_ptr = (int*)alloc((size_t)(N + 1) * 4);
    int*   cursor  = (int*)alloc((size_t)N * 4);
    int*   csr_src = (int*)alloc((size_t)E * 4);
    float* yA      = (float*)alloc((size_t)N * D * 4);
    float* yB      = (float*)alloc((size_t)N * D * 4);
    float* accS    = (float*)alloc((size_t)N * D * 4);
    int*   queues  = (int*)alloc((size_t)(L + 1) * 8 * 4);

    (void)hipMemsetAsync(deg, 0, (size_t)N * 4, stream);
    (void)hipMemsetAsync(cursor, 0, (size_t)N * 4, stream);
    (void)hipMemsetAsync(queues, 0, (size_t)(L + 1) * 8 * 4, stream);

    degree_kernel<<<(E + 255) / 256, 256, 0, stream>>>(col, deg, E);
    dinv_kernel<<<(N + 255) / 256, 256, 0, stream>>>(deg, dinv, N);
    scan_kernel<<<1, 1024, 0, stream>>>(deg, row_ptr, N);
    scatter_kernel<<<(E + 255) / 256, 256, 0, stream>>>(row, col, row_ptr, cursor,
                                                        csr_src, E);

    init_kernel<<<(N * 16 + 255) / 256, 256, 0, stream>>>((const float4*)emb, dinv,
                                                          (float4*)yA, (float4*)accS, N);

    const int nchunks = (N + 127) / 128;   // 704 chunks per XCD slice
    const int NB = 2048;                    // queue self-balances; extra blocks exit fast
    const float* yin = yA;
    float* yout = yB;
    for (int l = 0; l < L; ++l) {
        spmm8_kernel<<<NB, 256, 0, stream>>>(yin, yout, accS, row_ptr, csr_src, dinv,
                                             queues + (size_t)l * 8, N, nchunks, E);
        const float* t = yin;
        yin = yout;
        yout = (float*)t;
    }

    finalize_kernel<<<(N * 16 + 255) / 256, 256, 0, stream>>>(
        (const float4*)accS, (float4*)d_out, 1.0f / (float)(L + 1), N);
}

// Round 18
// 7293.779 us; speedup vs baseline: 6.9648x; 6.9648x over previous
//
#include <hip/hip_runtime.h>
#include <hip/hip_fp16.h>

#define D 64
// Baseline-skeleton SpMM (the only structure that has measured fast: 1 wave per
// dst node, 4 edge-groups x 16 lanes, shfl reduce) with two byte-cutting levers:
//  - y-transform: x_{l+1}=dinv*Sum y_l[src], y=dinv*x -> NO per-edge weights.
//  - y stored in fp16: a full 64-dim row = 128B = ONE cache line per gather
//    (fp32 was 2 lines). Accumulation/acc/output all stay fp32.
// Rounds 10/12/13/17 lesson: L2-placement schemes (XCD slices, tile phasing)
// all lost to the plain L3-served gather; granularity and total bytes are what
// matter. No nontemporal ops anywhere.

__global__ void degree_kernel(const int* __restrict__ col, int* __restrict__ deg, int E) {
    int e = blockIdx.x * blockDim.x + threadIdx.x;
    if (e < E) atomicAdd(&deg[col[e]], 1);
}

__global__ void dinv_kernel(const int* __restrict__ deg, float* __restrict__ dinv, int n) {
    int i = blockIdx.x * blockDim.x + threadIdx.x;
    if (i < n) {
        int d = deg[i];
        dinv[i] = (d > 0) ? rsqrtf((float)d) : 0.0f;
    }
}

// Single-workgroup exclusive scan over N elements (runs once per call).
__global__ __launch_bounds__(1024) void scan_kernel(const int* __restrict__ deg,
                                                    int* __restrict__ row_ptr, int n) {
    __shared__ int wsum[16];
    const int tid = threadIdx.x;
    const int lane = tid & 63;
    const int w = tid >> 6;
    int carry = 0;
    for (int base = 0; base < n; base += 1024) {
        int i = base + tid;
        int v = (i < n) ? deg[i] : 0;
        int x = v;
#pragma unroll
        for (int off = 1; off < 64; off <<= 1) {
            int y = __shfl_up(x, off);
            if (lane >= off) x += y;
        }
        if (lane == 63) wsum[w] = x;
        __syncthreads();
        if (w == 0 && lane < 16) {
            int s = wsum[lane];
#pragma unroll
            for (int off = 1; off < 16; off <<= 1) {
                int y = __shfl_up(s, off);
                if (lane >= off) s += y;
            }
            wsum[lane] = s;
        }
        __syncthreads();
        int pref = (w > 0) ? wsum[w - 1] : 0;
        if (i < n) row_ptr[i] = carry + pref + (x - v);
        carry += wsum[15];
        __syncthreads();
    }
    if (tid == 0) row_ptr[n] = carry;
}

// CSR build: only src ids (y-transform removed per-edge weights).
__global__ void scatter_kernel(const int* __restrict__ row, const int* __restrict__ col,
                               const int* __restrict__ row_ptr, int* __restrict__ cursor,
                               int* __restrict__ csr_src, int E) {
    int e = blockIdx.x * blockDim.x + threadIdx.x;
    if (e < E) {
        int s = row[e];
        int d = col[e];
        int pos = row_ptr[d] + atomicAdd(&cursor[d], 1);
        csr_src[pos] = s;
    }
}

// acc0 = emb (fp32, in d_out); y0 = half(dinv * emb), [node][64] half layout.
__global__ void init_kernel(const float4* __restrict__ emb, const float* __restrict__ dinv,
                            __half* __restrict__ y, float4* __restrict__ outAcc, int n) {
    int i = blockIdx.x * blockDim.x + threadIdx.x;   // over n*16 float4s
    if (i < n * 16) {
        int node = i >> 4;
        int t = i & 15;
        float dv = dinv[node];
        float4 v = emb[i];
        outAcc[i] = v;
        __half2 h0 = __float22half2_rn(make_float2(v.x * dv, v.y * dv));
        __half2 h1 = __float22half2_rn(make_float2(v.z * dv, v.w * dv));
        int2 wbits;
        wbits.x = __builtin_bit_cast(int, h0);
        wbits.y = __builtin_bit_cast(int, h1);
        *(int2*)(y + (size_t)node * D + t * 4) = wbits;
    }
}

// One wave per dst node. 4 edge-groups of 16 lanes; lane t of a group loads the
// 8B half4 of dims [4t,4t+4) -> one group gather = one 128B line. 2-deep
// software pipeline: indices prefetched 2 iterations ahead, gathers issued 1
// ahead. Wave-uniform loop bounds; tails handled with mask-FMAs (idx 0 is a
// safe hot line).
__global__ __launch_bounds__(256) void spmm_kernel(
    const __half* __restrict__ y_in, __half* __restrict__ y_out,
    float4* __restrict__ acc, const int* __restrict__ row_ptr,
    const int* __restrict__ csr_src, const float* __restrict__ dinv, int n) {
    int wv = (int)((blockIdx.x * blockDim.x + threadIdx.x) >> 6);
    int lane = threadIdx.x & 63;
    if (wv >= n) return;
    int g = lane >> 4;   // edge subgroup 0..3
    int t = lane & 15;   // half4 slot within the 64-dim row
    int beg = row_ptr[wv], end = row_ptr[wv + 1];
    float s0 = 0.f, s1 = 0.f, s2 = 0.f, s3 = 0.f;

    // pipeline prologue
    int e0 = beg + g;
    int i0 = 0; float m0 = 0.f;
    if (e0 < end) { i0 = csr_src[e0]; m0 = 1.f; }
    int e1 = e0 + 4;
    int i1 = 0; float m1 = 0.f;
    if (e1 < end) { i1 = csr_src[e1]; m1 = 1.f; }
    int2 r0 = *(const int2*)(y_in + (size_t)i0 * D + t * 4);

    for (int e = beg; e < end; e += 4) {
        // issue next gather (may be masked-dummy on the last iteration)
        int2 r1 = *(const int2*)(y_in + (size_t)i1 * D + t * 4);
        // prefetch index two iterations ahead
        int e2 = e + 8 + g;
        int i2 = 0; float m2 = 0.f;
        if (e2 < end) { i2 = csr_src[e2]; m2 = 1.f; }
        // consume current gather
        __half2 ha = __builtin_bit_cast(__half2, r0.x);
        __half2 hb = __builtin_bit_cast(__half2, r0.y);
        float2 fa = __half22float2(ha);
        float2 fb = __half22float2(hb);
        s0 = fmaf(m0, fa.x, s0);
        s1 = fmaf(m0, fa.y, s1);
        s2 = fmaf(m0, fb.x, s2);
        s3 = fmaf(m0, fb.y, s3);
        // rotate
        r0 = r1; m0 = m1; i1 = i2; m1 = m2;
    }

    // reduce the 4 edge-groups (lanes differing in bits 4,5)
    s0 += __shfl_xor(s0, 16); s1 += __shfl_xor(s1, 16);
    s2 += __shfl_xor(s2, 16); s3 += __shfl_xor(s3, 16);
    s0 += __shfl_xor(s0, 32); s1 += __shfl_xor(s1, 32);
    s2 += __shfl_xor(s2, 32); s3 += __shfl_xor(s3, 32);

    if (g == 0) {
        const float dv = dinv[wv];
        float x0 = dv * s0, x1 = dv * s1, x2 = dv * s2, x3 = dv * s3;  // x_{l+1}
        const int o = wv * 16 + t;
        float4 a = acc[o];
        a.x += x0; a.y += x1; a.z += x2; a.w += x3;
        acc[o] = a;
        __half2 h0 = __float22half2_rn(make_float2(dv * x0, dv * x1));  // y_{l+1}
        __half2 h1 = __float22half2_rn(make_float2(dv * x2, dv * x3));
        int2 wbits;
        wbits.x = __builtin_bit_cast(int, h0);
        wbits.y = __builtin_bit_cast(int, h1);
        *(int2*)(y_out + (size_t)wv * D + t * 4) = wbits;
    }
}

__global__ void scale_kernel(float4* __restrict__ out, float f, int n4) {
    int i = blockIdx.x * blockDim.x + threadIdx.x;
    if (i < n4) {
        float4 a = out[i];
        a.x *= f; a.y *= f; a.z *= f; a.w *= f;
        out[i] = a;
    }
}

extern "C" void kernel_launch(void* const* d_in, const int* in_sizes, int n_in,
                              void* d_out, int out_size, void* d_ws, size_t ws_size,
                              hipStream_t stream) {
    const float* emb = (const float*)d_in[0];
    const int* eidx = (const int*)d_in[1];
    const int N = in_sizes[0] / D;   // 90000
    const int E = in_sizes[1] / 2;   // 3000000
    const int L = 100;
    const int* row = eidx;       // edge_index[0]
    const int* col = eidx + E;   // edge_index[1]

    size_t off = 0;
    auto alloc = [&](size_t bytes) -> void* {
        void* p = (char*)d_ws + off;
        off += (bytes + 255) & ~(size_t)255;
        return p;
    };
    int*    deg     = (int*)alloc((size_t)N * 4);
    float*  dinv    = (float*)alloc((size_t)N * 4);
    int*    row_ptr = (int*)alloc((size_t)(N + 1) * 4);
    int*    cursor  = (int*)alloc((size_t)N * 4);
    int*    csr_src = (int*)alloc((size_t)E * 4);
    __half* yA      = (__half*)alloc((size_t)N * D * 2);
    __half* yB      = (__half*)alloc((size_t)N * D * 2);

    (void)hipMemsetAsync(deg, 0, (size_t)N * 4, stream);
    (void)hipMemsetAsync(cursor, 0, (size_t)N * 4, stream);

    degree_kernel<<<(E + 255) / 256, 256, 0, stream>>>(col, deg, E);
    dinv_kernel<<<(N + 255) / 256, 256, 0, stream>>>(deg, dinv, N);
    scan_kernel<<<1, 1024, 0, stream>>>(deg, row_ptr, N);
    scatter_kernel<<<(E + 255) / 256, 256, 0, stream>>>(row, col, row_ptr, cursor,
                                                        csr_src, E);

    float* out = (float*)d_out;
    init_kernel<<<(N * 16 + 255) / 256, 256, 0, stream>>>((const float4*)emb, dinv,
                                                          yA, (float4*)out, N);

    const __half* yin = yA;
    __half* yout = yB;
    for (int l = 0; l < L; ++l) {
        spmm_kernel<<<(N + 3) / 4, 256, 0, stream>>>(yin, yout, (float4*)out,
                                                     row_ptr, csr_src, dinv, N);
        const __half* tmp = yin;
        yin = yout;
        yout = (__half*)tmp;
    }

    const int n4 = N * D / 4;
    scale_kernel<<<(n4 + 255) / 256, 256, 0, stream>>>((float4*)out, 1.0f / (float)(L + 1), n4);
}

// Round 19
// 6134.044 us; speedup vs baseline: 8.2816x; 1.1891x over previous
//
#include <hip/hip_runtime.h>
#include <hip/hip_fp16.h>

#define D 64
// Baseline-skeleton SpMM + y-transform + fp16 y (one 128B line per gather).
// Round-19 change: 8 edge-groups x 8 lanes (int4 = 16B per lane) instead of
// 4 groups x 16 lanes -> 8 independent gather streams per wave (2x MLP) at
// identical traffic. Accumulation/acc/output all stay fp32.
// Rounds 10/12/13/17 lesson: L2-placement schemes lose; line count x line rate
// is what matters. No nontemporal ops anywhere.

__global__ void degree_kernel(const int* __restrict__ col, int* __restrict__ deg, int E) {
    int e = blockIdx.x * blockDim.x + threadIdx.x;
    if (e < E) atomicAdd(&deg[col[e]], 1);
}

__global__ void dinv_kernel(const int* __restrict__ deg, float* __restrict__ dinv, int n) {
    int i = blockIdx.x * blockDim.x + threadIdx.x;
    if (i < n) {
        int d = deg[i];
        dinv[i] = (d > 0) ? rsqrtf((float)d) : 0.0f;
    }
}

// Single-workgroup exclusive scan over N elements (runs once per call).
__global__ __launch_bounds__(1024) void scan_kernel(const int* __restrict__ deg,
                                                    int* __restrict__ row_ptr, int n) {
    __shared__ int wsum[16];
    const int tid = threadIdx.x;
    const int lane = tid & 63;
    const int w = tid >> 6;
    int carry = 0;
    for (int base = 0; base < n; base += 1024) {
        int i = base + tid;
        int v = (i < n) ? deg[i] : 0;
        int x = v;
#pragma unroll
        for (int off = 1; off < 64; off <<= 1) {
            int y = __shfl_up(x, off);
            if (lane >= off) x += y;
        }
        if (lane == 63) wsum[w] = x;
        __syncthreads();
        if (w == 0 && lane < 16) {
            int s = wsum[lane];
#pragma unroll
            for (int off = 1; off < 16; off <<= 1) {
                int y = __shfl_up(s, off);
                if (lane >= off) s += y;
            }
            wsum[lane] = s;
        }
        __syncthreads();
        int pref = (w > 0) ? wsum[w - 1] : 0;
        if (i < n) row_ptr[i] = carry + pref + (x - v);
        carry += wsum[15];
        __syncthreads();
    }
    if (tid == 0) row_ptr[n] = carry;
}

// CSR build: only src ids (y-transform removed per-edge weights).
__global__ void scatter_kernel(const int* __restrict__ row, const int* __restrict__ col,
                               const int* __restrict__ row_ptr, int* __restrict__ cursor,
                               int* __restrict__ csr_src, int E) {
    int e = blockIdx.x * blockDim.x + threadIdx.x;
    if (e < E) {
        int s = row[e];
        int d = col[e];
        int pos = row_ptr[d] + atomicAdd(&cursor[d], 1);
        csr_src[pos] = s;
    }
}

// acc0 = emb (fp32, in d_out); y0 = half(dinv * emb), [node][64] half layout.
__global__ void init_kernel(const float4* __restrict__ emb, const float* __restrict__ dinv,
                            __half* __restrict__ y, float4* __restrict__ outAcc, int n) {
    int i = blockIdx.x * blockDim.x + threadIdx.x;   // over n*16 float4s
    if (i < n * 16) {
        int node = i >> 4;
        int t = i & 15;
        float dv = dinv[node];
        float4 v = emb[i];
        outAcc[i] = v;
        __half2 h0 = __float22half2_rn(make_float2(v.x * dv, v.y * dv));
        __half2 h1 = __float22half2_rn(make_float2(v.z * dv, v.w * dv));
        int2 wbits;
        wbits.x = __builtin_bit_cast(int, h0);
        wbits.y = __builtin_bit_cast(int, h1);
        *(int2*)(y + (size_t)node * D + t * 4) = wbits;
    }
}

// One wave per dst node. 8 edge-groups of 8 lanes; lane t of a group loads the
// 16B int4 of dims [8t,8t+8) -> one group gather = one 128B line; 8 independent
// lines in flight per wave (+1 pipelined ahead). Indices prefetched 2 iterations
// ahead. Wave-uniform loop bounds; tails via mask-FMAs (idx 0 is a hot line).
__global__ __launch_bounds__(256) void spmm_kernel(
    const __half* __restrict__ y_in, __half* __restrict__ y_out,
    float4* __restrict__ acc, const int* __restrict__ row_ptr,
    const int* __restrict__ csr_src, const float* __restrict__ dinv, int n) {
    int wv = (int)((blockIdx.x * blockDim.x + threadIdx.x) >> 6);
    int lane = threadIdx.x & 63;
    if (wv >= n) return;
    int g = lane >> 3;   // edge subgroup 0..7
    int t = lane & 7;    // int4 slot within the 128B row
    int beg = row_ptr[wv], end = row_ptr[wv + 1];
    float s0 = 0.f, s1 = 0.f, s2 = 0.f, s3 = 0.f;
    float s4 = 0.f, s5 = 0.f, s6 = 0.f, s7 = 0.f;

    // pipeline prologue
    int e0 = beg + g;
    int i0 = 0; float m0 = 0.f;
    if (e0 < end) { i0 = csr_src[e0]; m0 = 1.f; }
    int e1 = e0 + 8;
    int i1 = 0; float m1 = 0.f;
    if (e1 < end) { i1 = csr_src[e1]; m1 = 1.f; }
    int4 r0 = *(const int4*)(y_in + (size_t)i0 * D + t * 8);

    for (int e = beg; e < end; e += 8) {
        // issue next gather (masked-dummy on the last iteration)
        int4 r1 = *(const int4*)(y_in + (size_t)i1 * D + t * 8);
        // prefetch index two iterations ahead
        int e2 = e + 16 + g;
        int i2 = 0; float m2 = 0.f;
        if (e2 < end) { i2 = csr_src[e2]; m2 = 1.f; }
        // consume current gather
        float2 f0 = __half22float2(__builtin_bit_cast(__half2, r0.x));
        float2 f1 = __half22float2(__builtin_bit_cast(__half2, r0.y));
        float2 f2 = __half22float2(__builtin_bit_cast(__half2, r0.z));
        float2 f3 = __half22float2(__builtin_bit_cast(__half2, r0.w));
        s0 = fmaf(m0, f0.x, s0); s1 = fmaf(m0, f0.y, s1);
        s2 = fmaf(m0, f1.x, s2); s3 = fmaf(m0, f1.y, s3);
        s4 = fmaf(m0, f2.x, s4); s5 = fmaf(m0, f2.y, s5);
        s6 = fmaf(m0, f3.x, s6); s7 = fmaf(m0, f3.y, s7);
        // rotate
        r0 = r1; m0 = m1; i1 = i2; m1 = m2;
    }

    // reduce the 8 edge-groups (lanes differing in bits 3,4,5)
#pragma unroll
    for (int off = 8; off < 64; off <<= 1) {
        s0 += __shfl_xor(s0, off); s1 += __shfl_xor(s1, off);
        s2 += __shfl_xor(s2, off); s3 += __shfl_xor(s3, off);
        s4 += __shfl_xor(s4, off); s5 += __shfl_xor(s5, off);
        s6 += __shfl_xor(s6, off); s7 += __shfl_xor(s7, off);
    }

    if (g == 0) {
        const float dv = dinv[wv];
        float x0 = dv * s0, x1 = dv * s1, x2 = dv * s2, x3 = dv * s3;  // x_{l+1}
        float x4 = dv * s4, x5 = dv * s5, x6 = dv * s6, x7 = dv * s7;
        const int o = wv * 16 + t * 2;   // dims [8t, 8t+8) = float4s 2t, 2t+1
        float4 a = acc[o];
        a.x += x0; a.y += x1; a.z += x2; a.w += x3;
        acc[o] = a;
        float4 b = acc[o + 1];
        b.x += x4; b.y += x5; b.z += x6; b.w += x7;
        acc[o + 1] = b;
        __half2 h0 = __float22half2_rn(make_float2(dv * x0, dv * x1));  // y_{l+1}
        __half2 h1 = __float22half2_rn(make_float2(dv * x2, dv * x3));
        __half2 h2 = __float22half2_rn(make_float2(dv * x4, dv * x5));
        __half2 h3 = __float22half2_rn(make_float2(dv * x6, dv * x7));
        int4 wbits;
        wbits.x = __builtin_bit_cast(int, h0);
        wbits.y = __builtin_bit_cast(int, h1);
        wbits.z = __builtin_bit_cast(int, h2);
        wbits.w = __builtin_bit_cast(int, h3);
        *(int4*)(y_out + (size_t)wv * D + t * 8) = wbits;
    }
}

__global__ void scale_kernel(float4* __restrict__ out, float f, int n4) {
    int i = blockIdx.x * blockDim.x + threadIdx.x;
    if (i < n4) {
        float4 a = out[i];
        a.x *= f; a.y *= f; a.z *= f; a.w *= f;
        out[i] = a;
    }
}

extern "C" void kernel_launch(void* const* d_in, const int* in_sizes, int n_in,
                              void* d_out, int out_size, void* d_ws, size_t ws_size,
                              hipStream_t stream) {
    const float* emb = (const float*)d_in[0];
    const int* eidx = (const int*)d_in[1];
    const int N = in_sizes[0] / D;   // 90000
    const int E = in_sizes[1] / 2;   // 3000000
    const int L = 100;
    const int* row = eidx;       // edge_index[0]
    const int* col = eidx + E;   // edge_index[1]

    size_t off = 0;
    auto alloc = [&](size_t bytes) -> void* {
        void* p = (char*)d_ws + off;
        off += (bytes + 255) & ~(size_t)255;
        return p;
    };
    int*    deg     = (int*)alloc((size_t)N * 4);
    float*  dinv    = (float*)alloc((size_t)N * 4);
    int*    row_ptr = (int*)alloc((size_t)(N + 1) * 4);
    int*    cursor  = (int*)alloc((size_t)N * 4);
    int*    csr_src = (int*)alloc((size_t)E * 4);
    __half* yA      = (__half*)alloc((size_t)N * D * 2);
    __half* yB      = (__half*)alloc((size_t)N * D * 2);

    (void)hipMemsetAsync(deg, 0, (size_t)N * 4, stream);
    (void)hipMemsetAsync(cursor, 0, (size_t)N * 4, stream);

    degree_kernel<<<(E + 255) / 256, 256, 0, stream>>>(col, deg, E);
    dinv_kernel<<<(N + 255) / 256, 256, 0, stream>>>(deg, dinv, N);
    scan_kernel<<<1, 1024, 0, stream>>>(deg, row_ptr, N);
    scatter_kernel<<<(E + 255) / 256, 256, 0, stream>>>(row, col, row_ptr, cursor,
                                                        csr_src, E);

    float* out = (float*)d_out;
    init_kernel<<<(N * 16 + 255) / 256, 256, 0, stream>>>((const float4*)emb, dinv,
                                                          yA, (float4*)out, N);

    const __half* yin = yA;
    __half* yout = yB;
    for (int l = 0; l < L; ++l) {
        spmm_kernel<<<(N + 3) / 4, 256, 0, stream>>>(yin, yout, (float4*)out,
                                                     row_ptr, csr_src, dinv, N);
        const __half* tmp = yin;
        yin = yout;
        yout = (__half*)tmp;
    }

    const int n4 = N * D / 4;
    scale_kernel<<<(n4 + 255) / 256, 256, 0, stream>>>((float4*)out, 1.0f / (float)(L + 1), n4);
}